// Round 1
// baseline (267.618 us; speedup 1.0000x reference)
//
#include <hip/hip_runtime.h>

typedef float f32x4 __attribute__((ext_vector_type(4)));
typedef short bf16x8 __attribute__((ext_vector_type(8)));

__device__ __forceinline__ unsigned short f2bf(float f) {
  unsigned u = __builtin_bit_cast(unsigned, f);
  u = (u + 0x7FFFu + ((u >> 16) & 1u)) >> 16;
  return (unsigned short)u;
}

// ---------------------------------------------------------------------------
// Kernel 1: x (B,C,H,W) f32  ->  x_t (B,H,W,C) bf16, plus per-(b,c,y) row sums
// One block per (y,b): full 128c x 128col transpose tile through LDS.
// LDS tile is XOR-swizzled on the channel index so both the u16 scatter
// writes and the 16B vector reads stay low-conflict.
// ---------------------------------------------------------------------------
__global__ __launch_bounds__(256) void k_transpose(const float* __restrict__ x,
                                                   unsigned short* __restrict__ xt,
                                                   float* __restrict__ rowsum) {
  __shared__ unsigned short tile[128][128];
  __shared__ float psum[128][8];
  const int y = blockIdx.x, b = blockIdx.y;
  const int t = threadIdx.x;
  const int colb = (t & 7) * 16;   // 16-col chunk
  const int cp = t >> 3;           // 0..31 channel within chunk
  const int swz = (t & 7) << 3;    // col>>4 == t&7 for all 16 cols this thread touches
  for (int ci = 0; ci < 4; ++ci) {
    const int c = ci * 32 + cp;
    const int c2 = c ^ swz;
    const float* src = x + (((size_t)(b * 128 + c) * 128 + y) * 128 + colb);
    float s = 0.f;
#pragma unroll
    for (int j = 0; j < 16; j += 4) {
      float4 v = *(const float4*)(src + j);
      s += v.x + v.y + v.z + v.w;
      tile[colb + j + 0][c2] = f2bf(v.x);
      tile[colb + j + 1][c2] = f2bf(v.y);
      tile[colb + j + 2][c2] = f2bf(v.z);
      tile[colb + j + 3][c2] = f2bf(v.w);
    }
    psum[c][t & 7] = s;
  }
  __syncthreads();
  // write x_t: fully coalesced 256B/row segments
#pragma unroll
  for (int it = 0; it < 8; ++it) {
    const int slot = t + it * 256;        // 0..2047
    const int col = slot >> 4;            // 0..127
    const int cg = (slot & 15) * 8;       // channel group of 8
    const int c2 = cg ^ (((col >> 4) & 7) << 3);
    uint4 vv = *(const uint4*)&tile[col][c2];
    *(uint4*)(xt + (((size_t)(b * 128 + y) * 128 + col) * 128 + cg)) = vv;
  }
  if (t < 128) {
    float r = 0.f;
#pragma unroll
    for (int j = 0; j < 8; ++j) r += psum[t][j];
    rowsum[((size_t)b * 128 + t) * 128 + y] = r;  // [b][c][y]
  }
}

// ---------------------------------------------------------------------------
// Kernel 2: rowsums -> pooled -> attention MLP -> softmax -> attn, agg_b
// ---------------------------------------------------------------------------
__global__ __launch_bounds__(128) void k_attn(const float* __restrict__ rowsum,
                                              const float* __restrict__ aw1,
                                              const float* __restrict__ ab1,
                                              const float* __restrict__ aw2,
                                              const float* __restrict__ ab2,
                                              const float* __restrict__ bias,
                                              float* __restrict__ attn,
                                              float* __restrict__ aggb) {
  __shared__ float pooled[128];
  __shared__ float h[32];
  __shared__ float at[4];
  const int b = blockIdx.x, t = threadIdx.x;
  const float* rs = rowsum + (size_t)(b * 128 + t) * 128;
  float s = 0.f;
  for (int yy = 0; yy < 128; ++yy) s += rs[yy];
  pooled[t] = s * (1.f / 16384.f);
  __syncthreads();
  if (t < 32) {
    float hv = ab1[t];
    for (int c = 0; c < 128; ++c) hv += pooled[c] * aw1[t * 128 + c];
    h[t] = fmaxf(hv, 0.f);
  }
  __syncthreads();
  if (t < 4) {
    float sc = ab2[t];
    for (int a = 0; a < 32; ++a) sc += h[a] * aw2[t * 32 + a];
    at[t] = sc * (1.f / 30.f);
  }
  __syncthreads();
  if (t == 0) {
    float m = fmaxf(fmaxf(at[0], at[1]), fmaxf(at[2], at[3]));
    float e0 = __expf(at[0] - m), e1 = __expf(at[1] - m);
    float e2 = __expf(at[2] - m), e3 = __expf(at[3] - m);
    float inv = 1.f / (e0 + e1 + e2 + e3);
    at[0] = e0 * inv; at[1] = e1 * inv; at[2] = e2 * inv; at[3] = e3 * inv;
  }
  __syncthreads();
  if (t < 4) attn[b * 4 + t] = at[t];
  float ab = 0.f;
  for (int k = 0; k < 4; ++k) ab += at[k] * bias[k * 128 + t];
  aggb[b * 128 + t] = ab;
}

// ---------------------------------------------------------------------------
// Kernel 3: aggregate weights over K and cast to bf16 in MFMA-A layout:
//   aggw[(((b*9+pq)*4+cc)*128+o)*32 + c']   (c = cc*32+c')
// ---------------------------------------------------------------------------
__global__ __launch_bounds__(256) void k_aggw(const float* __restrict__ weight,
                                              const float* __restrict__ attn,
                                              unsigned short* __restrict__ aggw) {
  const int fid = blockIdx.x * 256 + threadIdx.x;  // == output layout index
  const int cl = fid & 31;
  const int o = (fid >> 5) & 127;
  const int cc = (fid >> 12) & 3;
  const int rest = fid >> 14;       // b*9 + pq
  const int pq = rest % 9;
  const int b = rest / 9;
  const int c = cc * 32 + cl;
  const size_t src = (size_t)o * 1152 + (size_t)c * 9 + pq;
  float s = attn[b * 4 + 0] * weight[src]
          + attn[b * 4 + 1] * weight[src + 147456]
          + attn[b * 4 + 2] * weight[src + 2 * 147456]
          + attn[b * 4 + 3] * weight[src + 3 * 147456];
  aggw[fid] = f2bf(s);
}

// ---------------------------------------------------------------------------
// Kernel 4: the conv. Implicit GEMM, one block per (output row y, sample b).
// M = Cout = 128, N = 128 px, K = 1152 (9 taps x 4 chunks of 32 ch).
// 4 waves in 2x2; each wave owns a 64x64 tile via 4x4 mfma_f32_16x16x32_bf16.
// No LDS: all fragments are 16B global loads from L2/L3-hot x_t / aggw.
// ---------------------------------------------------------------------------
__global__ __launch_bounds__(256) void k_conv(const unsigned short* __restrict__ xt,
                                              const unsigned short* __restrict__ aggw,
                                              const float* __restrict__ aggb,
                                              float* __restrict__ out) {
  const int y = blockIdx.x, b = blockIdx.y;
  const int t = threadIdx.x;
  const int lane = t & 63, wid = t >> 6;
  const int mw = wid >> 1, nw = wid & 1;
  const int l15 = lane & 15, lk = lane >> 4;
  f32x4 acc[4][4] = {};
  // A base: + m-row(l15) within 16, + k-offset lk*8, + wave m-offset
  const unsigned short* awp = aggw + (size_t)b * 147456 + (size_t)l15 * 32 + lk * 8 + mw * (64 * 32);
  for (int p = 0; p < 3; ++p) {
    const int gy = y + p - 1;
    if (gy < 0 || gy >= 128) continue;  // uniform across block
    const unsigned short* xrow = xt + ((size_t)(b * 128 + gy) * 128) * 128 + lk * 8;
    for (int q = 0; q < 3; ++q) {
      const int colq = nw * 64 + l15 + q - 1;
#pragma unroll
      for (int cc = 0; cc < 4; ++cc) {
        const unsigned short* wb = awp + (size_t)((p * 3 + q) * 4 + cc) * 4096;
        bf16x8 a[4];
#pragma unroll
        for (int mi = 0; mi < 4; ++mi) a[mi] = *(const bf16x8*)(wb + mi * 512);
        bf16x8 bb[4];
#pragma unroll
        for (int ni = 0; ni < 4; ++ni) {
          const int col = colq + ni * 16;
          if (col >= 0 && col < 128)
            bb[ni] = *(const bf16x8*)(xrow + (size_t)col * 128 + cc * 32);
          else
            bb[ni] = (bf16x8)0;
        }
#pragma unroll
        for (int mi = 0; mi < 4; ++mi)
#pragma unroll
          for (int ni = 0; ni < 4; ++ni)
            acc[mi][ni] = __builtin_amdgcn_mfma_f32_16x16x32_bf16(a[mi], bb[ni], acc[mi][ni], 0, 0, 0);
      }
    }
  }
  // epilogue: C/D layout col = lane&15 (px), row = (lane>>4)*4 + r (Cout)
  const int colb = nw * 64 + l15;
#pragma unroll
  for (int mi = 0; mi < 4; ++mi) {
    const int o = mw * 64 + mi * 16 + lk * 4;
#pragma unroll
    for (int r = 0; r < 4; ++r) {
      const float bsv = aggb[b * 128 + o + r];
      float* orow = out + ((size_t)(b * 128 + o + r) * 128 + y) * 128 + colb;
      orow[0]  = acc[mi][0][r] + bsv;
      orow[16] = acc[mi][1][r] + bsv;
      orow[32] = acc[mi][2][r] + bsv;
      orow[48] = acc[mi][3][r] + bsv;
    }
  }
}

// ---------------------------------------------------------------------------
extern "C" void kernel_launch(void* const* d_in, const int* in_sizes, int n_in,
                              void* d_out, int out_size, void* d_ws, size_t ws_size,
                              hipStream_t stream) {
  const float* x      = (const float*)d_in[0];
  const float* weight = (const float*)d_in[1];
  const float* bias   = (const float*)d_in[2];
  const float* aw1    = (const float*)d_in[3];
  const float* ab1    = (const float*)d_in[4];
  const float* aw2    = (const float*)d_in[5];
  const float* ab2    = (const float*)d_in[6];
  float* out = (float*)d_out;

  char* ws = (char*)d_ws;
  unsigned short* xt   = (unsigned short*)ws;                       // 67108864 B
  unsigned short* aggw = (unsigned short*)(ws + 67108864);          //  4718592 B
  float* rowsum        = (float*)(ws + 67108864 + 4718592);         //  1048576 B
  float* attn          = (float*)(ws + 67108864 + 4718592 + 1048576);        // 256 B
  float* aggb          = (float*)(ws + 67108864 + 4718592 + 1048576 + 256);  // 8192 B

  hipLaunchKernelGGL(k_transpose, dim3(128, 16), dim3(256), 0, stream, x, xt, rowsum);
  hipLaunchKernelGGL(k_attn, dim3(16), dim3(128), 0, stream,
                     rowsum, aw1, ab1, aw2, ab2, bias, attn, aggb);
  hipLaunchKernelGGL(k_aggw, dim3(9216), dim3(256), 0, stream, weight, attn, aggw);
  hipLaunchKernelGGL(k_conv, dim3(128, 16), dim3(256), 0, stream, xt, aggw, aggb, out);
}